// Round 5
// baseline (346.547 us; speedup 1.0000x reference)
//
#include <hip/hip_runtime.h>
#include <hip/hip_fp16.h>

#define C  64
#define C8 8
#define EPSV 1e-5f
// k = int(0.6*64) = 38 -> threshold = 38th largest = ascending index 26

__device__ __forceinline__ float silu_f(float v) {
    return v * (1.f / (1.f + __expf(-v)));
}

// One block = (b, d, 4-row h-band), 256 threads.
// Phase 1: depthwise 5x5 conv + BN1 + SiLU for all 64 c of the band's 256
//          locations -> y1s (fp16 LDS); band's x values -> xs (fp16 LDS),
//          harvested from the conv's own register data (no extra loads).
// Phase 2: thread-per-location, ALL loads from LDS: pw1+BN2+SiLU+pw2, attn,
//          in-register bitonic top-k, epilogue. Only global ops: 64 coalesced
//          fire-and-forget stores.
__global__ __launch_bounds__(256, 2) void fused_kernel(
    const float* __restrict__ x, const float* __restrict__ w_dw,
    const float* __restrict__ g1, const float* __restrict__ be1,
    const float* __restrict__ mu1, const float* __restrict__ va1,
    const float* __restrict__ w1, const float* __restrict__ b1,
    const float* __restrict__ g2, const float* __restrict__ be2,
    const float* __restrict__ mu2, const float* __restrict__ va2,
    const float* __restrict__ w2, const float* __restrict__ b2,
    const float* __restrict__ alphap, float* __restrict__ out)
{
    // [loc][swz(c,loc)], swz = (c+loc)&63. fp16 (2B): bank = (loc*32 + swz/2)%32
    // = (swz>>1)&31. Phase-1 write lanes (c,strip): swz distinct -> 2-way, free.
    // Phase-2 read lanes (loc): swz covers 0..63 -> 2-way, free.
    __shared__ __half y1s[256 * 64];   // 32 KB
    __shared__ __half xs [256 * 64];   // 32 KB

    const int blk = blockIdx.x;        // 1024 = b*256 + d*16 + hb
    const int hb = blk & 15;
    const int d  = (blk >> 4) & 15;
    const int b  = blk >> 8;
    const int h0 = hb * 4;
    const int tid = threadIdx.x;

    // ---------------- phase 1: depthwise conv, rows h0..h0+3
    {
        const int c   = tid >> 2;          // 0..63
        const int w16 = (tid & 3) * 16;    // output cols w16..w16+15
        const int q   = w16 >> 2;

        float wk[25];
#pragma unroll
        for (int i = 0; i < 25; ++i) wk[i] = w_dw[c * 25 + i];
        const float scale = g1[c] * rsqrtf(va1[c] + EPSV);
        const float shift = be1[c] - mu1[c] * scale;
        const long xbase = ((long)(b * C + c) * 16 + d) * 4096;

        float acc[4][16];
#pragma unroll
        for (int i = 0; i < 4; ++i)
#pragma unroll
            for (int ow = 0; ow < 16; ++ow) acc[i][ow] = 0.f;

#pragma unroll
        for (int j = 0; j < 8; ++j) {      // input row r = h0 + j - 2
            const int r = h0 + j - 2;
            if (r >= 0 && r < 64) {
                const float4* rowp = (const float4*)(x + xbase + r * 64);
                const float4 z = make_float4(0.f, 0.f, 0.f, 0.f);
                float4 u0 = (q > 0)  ? rowp[q - 1] : z;
                float4 u1 = rowp[q];
                float4 u2 = rowp[q + 1];
                float4 u3 = rowp[q + 2];
                float4 u4 = rowp[q + 3];
                float4 u5 = (q < 12) ? rowp[q + 4] : z;
                // vals[v] = x[row r, col w16 - 4 + v]
                float vals[24] = {u0.x,u0.y,u0.z,u0.w, u1.x,u1.y,u1.z,u1.w,
                                  u2.x,u2.y,u2.z,u2.w, u3.x,u3.y,u3.z,u3.w,
                                  u4.x,u4.y,u4.z,u4.w, u5.x,u5.y,u5.z,u5.w};
                // band rows pass through here (j in [2,5]) -> stage x to LDS
                if (j >= 2 && j <= 5) {
#pragma unroll
                    for (int ow = 0; ow < 16; ++ow) {
                        const int loc = (j - 2) * 64 + w16 + ow;
                        xs[loc * 64 + ((c + loc) & 63)] = __float2half(vals[ow + 4]);
                    }
                }
#pragma unroll
                for (int i = 0; i < 4; ++i) {
                    if (i <= j && (j - i) <= 4) {   // kernel row kr = j - i
                        const int kr = j - i;
#pragma unroll
                        for (int kc = 0; kc < 5; ++kc) {
                            const float kw = wk[kr * 5 + kc];
#pragma unroll
                            for (int ow = 0; ow < 16; ++ow)
                                acc[i][ow] += kw * vals[ow + kc + 2];
                        }
                    }
                }
            }
        }
#pragma unroll
        for (int i = 0; i < 4; ++i)
#pragma unroll
            for (int ow = 0; ow < 16; ++ow) {
                const int loc = i * 64 + w16 + ow;
                y1s[loc * 64 + ((c + loc) & 63)] =
                    __float2half(silu_f(acc[i][ow] * scale + shift));
            }
    }
    __syncthreads();

    // ---------------- phase 2: pw1 + BN2 + SiLU + pw2, attn, top-k, epilogue
    {
        const int loc = tid;               // row = tid>>6, w = tid&63

        // pw1 from LDS x (fp16)
        float s1[C8];
#pragma unroll
        for (int o = 0; o < C8; ++o) s1[o] = 0.f;
#pragma unroll
        for (int c = 0; c < C; ++c) {
            const float xc = __half2float(xs[loc * 64 + ((c + loc) & 63)]);
#pragma unroll
            for (int o = 0; o < C8; ++o) s1[o] += w1[o * C + c] * xc;
        }
        float hh[C8];
#pragma unroll
        for (int o = 0; o < C8; ++o) {
            const float sc = g2[o] * rsqrtf(va2[o] + EPSV);
            hh[o] = silu_f((s1[o] + b1[o] - mu2[o]) * sc + be2[o]);
        }

        // attn: a[] kept for epilogue (VGPR is free: LDS caps blocks/CU at 2)
        float a[C], t[C];
#pragma unroll
        for (int c = 0; c < C; ++c) {
            const float y1v = __half2float(y1s[loc * 64 + ((c + loc) & 63)]);
            float y2 = b2[c];
#pragma unroll
            for (int o = 0; o < C8; ++o) y2 += w2[c * C8 + o] * hh[o];
            const float av = y1v * y2;
            a[c] = av;
            t[c] = av;
        }

        // in-register bitonic sort (ascending) of 64 values
#pragma unroll
        for (int k = 2; k <= 64; k <<= 1) {
#pragma unroll
            for (int j = k >> 1; j > 0; j >>= 1) {
#pragma unroll
                for (int i = 0; i < 64; ++i) {
                    const int l = i ^ j;
                    if (l > i) {
                        const float u = t[i], v = t[l];
                        const float mn = fminf(u, v), mx = fmaxf(u, v);
                        if ((i & k) == 0) { t[i] = mn; t[l] = mx; }
                        else              { t[i] = mx; t[l] = mn; }
                    }
                }
            }
        }
        const float thr = t[26];          // 38th largest of 64
        const float alpha = alphap[0];

        const int rg = d * 4096 + (h0 + (tid >> 6)) * 64 + (tid & 63);
        float* op = out + (long)b * (C * 65536) + rg;

        // epilogue: all inputs from registers/LDS; only coalesced stores go out
#pragma unroll
        for (int c = 0; c < C; ++c) {
            const float xc = __half2float(xs[loc * 64 + ((c + loc) & 63)]);
            const float av = a[c];
            op[(long)c * 65536] = xc + ((av >= thr) ? alpha * av : 0.f);
        }
    }
}

extern "C" void kernel_launch(void* const* d_in, const int* in_sizes, int n_in,
                              void* d_out, int out_size, void* d_ws, size_t ws_size,
                              hipStream_t stream) {
    const float* x    = (const float*)d_in[0];
    const float* w_dw = (const float*)d_in[1];
    const float* g1   = (const float*)d_in[2];
    const float* be1  = (const float*)d_in[3];
    const float* mu1  = (const float*)d_in[4];
    const float* va1  = (const float*)d_in[5];
    const float* w1   = (const float*)d_in[6];
    const float* b1   = (const float*)d_in[7];
    const float* g2   = (const float*)d_in[8];
    const float* be2  = (const float*)d_in[9];
    const float* mu2  = (const float*)d_in[10];
    const float* va2  = (const float*)d_in[11];
    const float* w2   = (const float*)d_in[12];
    const float* b2   = (const float*)d_in[13];
    const float* alp  = (const float*)d_in[14];
    float* out = (float*)d_out;

    // grid: b(4) x d(16) x h-band(16) = 1024 blocks
    fused_kernel<<<1024, 256, 0, stream>>>(
        x, w_dw, g1, be1, mu1, va1, w1, b1, g2, be2, mu2, va2, w2, b2, alp, out);
}

// Round 6
// 217.137 us; speedup vs baseline: 1.5960x; 1.5960x over previous
//
#include <hip/hip_runtime.h>
#include <hip/hip_fp16.h>

#define C  64
#define C8 8
#define EPSV 1e-5f
// k = int(0.6*64) = 38 -> threshold = 38th largest = ascending index 26

__device__ __forceinline__ float silu_f(float v) {
    return v * (1.f / (1.f + __expf(-v)));
}

// LDS layout for xs/y1s: [c][256 fp16] with chunk-XOR swizzle:
//   element (c, loc) lives at  c*256 + (loc ^ ((c&7)*8))
// Phase-1 writes: 8 consecutive loc (aligned) for fixed c -> one 16-B chunk ->
//   ds_write_b128; per 16-lane group each 4-bank range gets 2 lanes (free).
// Phase-2 reads: c uniform across lanes, loc=lane -> 8 lane-groups hit 8
//   distinct 4-bank ranges, lane pairs share a 32-bit word (broadcast) -> free.
__global__ __launch_bounds__(256) void fused_kernel(
    const float* __restrict__ x, const float* __restrict__ w_dw,
    const float* __restrict__ g1, const float* __restrict__ be1,
    const float* __restrict__ mu1, const float* __restrict__ va1,
    const float* __restrict__ w1, const float* __restrict__ b1,
    const float* __restrict__ g2, const float* __restrict__ be2,
    const float* __restrict__ mu2, const float* __restrict__ va2,
    const float* __restrict__ w2, const float* __restrict__ b2,
    const float* __restrict__ alphap, float* __restrict__ out)
{
    __shared__ __align__(16) __half y1s[C * 256];   // 32 KB
    __shared__ __align__(16) __half xs [C * 256];   // 32 KB

    const int blk = blockIdx.x;        // 1024 = b*256 + d*16 + hb
    const int hb = blk & 15;
    const int d  = (blk >> 4) & 15;
    const int b  = blk >> 8;
    const int h0 = hb * 4;
    const int tid = threadIdx.x;

    // ---------------- phase 1: depthwise conv rows h0..h0+3, stage x + y1 to LDS
    {
        const int c     = tid >> 2;        // 0..63
        const int strip = tid & 3;
        const int w16   = strip * 16;      // output cols w16..w16+15
        const int q     = w16 >> 2;
        const int csw   = (c & 7) * 8;     // chunk-XOR term (in elements)

        float wk[25];
#pragma unroll
        for (int i = 0; i < 25; ++i) wk[i] = w_dw[c * 25 + i];
        const float scale = g1[c] * rsqrtf(va1[c] + EPSV);
        const float shift = be1[c] - mu1[c] * scale;
        const long xbase = ((long)(b * C + c) * 16 + d) * 4096;

        float acc[4][16];
#pragma unroll
        for (int i = 0; i < 4; ++i)
#pragma unroll
            for (int ow = 0; ow < 16; ++ow) acc[i][ow] = 0.f;

#pragma unroll
        for (int j = 0; j < 8; ++j) {      // input row r = h0 + j - 2
            const int r = h0 + j - 2;
            if (r >= 0 && r < 64) {
                const float4* rowp = (const float4*)(x + xbase + r * 64);
                const float4 z = make_float4(0.f, 0.f, 0.f, 0.f);
                float4 u0 = (q > 0)  ? rowp[q - 1] : z;
                float4 u1 = rowp[q];
                float4 u2 = rowp[q + 1];
                float4 u3 = rowp[q + 2];
                float4 u4 = rowp[q + 3];
                float4 u5 = (q < 12) ? rowp[q + 4] : z;
                // vals[v] = x[row r, col w16 - 4 + v]
                float vals[24] = {u0.x,u0.y,u0.z,u0.w, u1.x,u1.y,u1.z,u1.w,
                                  u2.x,u2.y,u2.z,u2.w, u3.x,u3.y,u3.z,u3.w,
                                  u4.x,u4.y,u4.z,u4.w, u5.x,u5.y,u5.z,u5.w};
                // band rows (j in [2,5]) pass through here -> stage x to LDS
                if (j >= 2 && j <= 5) {
                    const int i = j - 2;
                    const int chunkbase = i * 8 + 2 * strip;   // (loc>>3)
#pragma unroll
                    for (int t = 0; t < 2; ++t) {
                        const int p = (chunkbase + t) ^ (c & 7);
                        union { __half2 h[4]; float4 f; } u;
#pragma unroll
                        for (int m = 0; m < 4; ++m)
                            u.h[m] = __floats2half2_rn(vals[4 + t * 8 + 2 * m],
                                                       vals[4 + t * 8 + 2 * m + 1]);
                        *(float4*)&xs[c * 256 + p * 8] = u.f;
                    }
                }
#pragma unroll
                for (int i = 0; i < 4; ++i) {
                    if (i <= j && (j - i) <= 4) {   // kernel row kr = j - i
                        const int kr = j - i;
#pragma unroll
                        for (int kc = 0; kc < 5; ++kc) {
                            const float kw = wk[kr * 5 + kc];
#pragma unroll
                            for (int ow = 0; ow < 16; ++ow)
                                acc[i][ow] += kw * vals[ow + kc + 2];
                        }
                    }
                }
            }
        }
#pragma unroll
        for (int i = 0; i < 4; ++i) {
            float o[16];
#pragma unroll
            for (int ow = 0; ow < 16; ++ow)
                o[ow] = silu_f(acc[i][ow] * scale + shift);
            const int chunkbase = i * 8 + 2 * strip;
#pragma unroll
            for (int t = 0; t < 2; ++t) {
                const int p = (chunkbase + t) ^ (c & 7);
                union { __half2 h[4]; float4 f; } u;
#pragma unroll
                for (int m = 0; m < 4; ++m)
                    u.h[m] = __floats2half2_rn(o[t * 8 + 2 * m], o[t * 8 + 2 * m + 1]);
                *(float4*)&y1s[c * 256 + p * 8] = u.f;
            }
        }
    }
    __syncthreads();

    // ---------------- phase 2: pw1 + BN2 + SiLU + pw2, attn, top-k, epilogue
    {
        const int loc = tid;

        // pw1 from LDS x
        float s1[C8];
#pragma unroll
        for (int o = 0; o < C8; ++o) s1[o] = 0.f;
#pragma unroll
        for (int c = 0; c < C; ++c) {
            const float xc = __half2float(xs[c * 256 + (loc ^ ((c & 7) << 3))]);
#pragma unroll
            for (int o = 0; o < C8; ++o) s1[o] += w1[o * C + c] * xc;
        }
        float hh[C8];
#pragma unroll
        for (int o = 0; o < C8; ++o) {
            const float sc = g2[o] * rsqrtf(va2[o] + EPSV);
            hh[o] = silu_f((s1[o] + b1[o] - mu2[o]) * sc + be2[o]);
        }

        // attn: keep a[] for the epilogue (VGPR free: LDS caps at 2 blocks/CU)
        float a[C], t[C];
#pragma unroll
        for (int c = 0; c < C; ++c) {
            const float y1v = __half2float(y1s[c * 256 + (loc ^ ((c & 7) << 3))]);
            float y2 = b2[c];
#pragma unroll
            for (int o = 0; o < C8; ++o) y2 += w2[c * C8 + o] * hh[o];
            const float av = y1v * y2;
            a[c] = av;
            t[c] = av;
        }

        // in-register bitonic sort (ascending) of 64 values
#pragma unroll
        for (int k = 2; k <= 64; k <<= 1) {
#pragma unroll
            for (int j = k >> 1; j > 0; j >>= 1) {
#pragma unroll
                for (int i = 0; i < 64; ++i) {
                    const int l = i ^ j;
                    if (l > i) {
                        const float u = t[i], v = t[l];
                        const float mn = fminf(u, v), mx = fmaxf(u, v);
                        if ((i & k) == 0) { t[i] = mn; t[l] = mx; }
                        else              { t[i] = mx; t[l] = mn; }
                    }
                }
            }
        }
        const float thr = t[26];          // 38th largest of 64
        const float alpha = alphap[0];

        const int rg = d * 4096 + (h0 + (tid >> 6)) * 64 + (tid & 63);
        float* op = out + (long)b * (C * 65536) + rg;

        // epilogue: inputs from registers/LDS; only coalesced stores go global
#pragma unroll
        for (int c = 0; c < C; ++c) {
            const float xc = __half2float(xs[c * 256 + (loc ^ ((c & 7) << 3))]);
            const float av = a[c];
            op[(long)c * 65536] = xc + ((av >= thr) ? alpha * av : 0.f);
        }
    }
}

extern "C" void kernel_launch(void* const* d_in, const int* in_sizes, int n_in,
                              void* d_out, int out_size, void* d_ws, size_t ws_size,
                              hipStream_t stream) {
    const float* x    = (const float*)d_in[0];
    const float* w_dw = (const float*)d_in[1];
    const float* g1   = (const float*)d_in[2];
    const float* be1  = (const float*)d_in[3];
    const float* mu1  = (const float*)d_in[4];
    const float* va1  = (const float*)d_in[5];
    const float* w1   = (const float*)d_in[6];
    const float* b1   = (const float*)d_in[7];
    const float* g2   = (const float*)d_in[8];
    const float* be2  = (const float*)d_in[9];
    const float* mu2  = (const float*)d_in[10];
    const float* va2  = (const float*)d_in[11];
    const float* w2   = (const float*)d_in[12];
    const float* b2   = (const float*)d_in[13];
    const float* alp  = (const float*)d_in[14];
    float* out = (float*)d_out;

    // grid: b(4) x d(16) x h-band(16) = 1024 blocks
    fused_kernel<<<1024, 256, 0, stream>>>(
        x, w_dw, g1, be1, mu1, va1, w1, b1, g2, be2, mu2, va2, w2, b2, alp, out);
}